// Round 17
// baseline (74.075 us; speedup 1.0000x reference)
//
#include <hip/hip_runtime.h>

#define NV 1084
#define NVPAD 1088
#define NBATCH 8   // batches per joints block

typedef __attribute__((ext_vector_type(8))) short short8v;
typedef __attribute__((ext_vector_type(4))) float f32x4;

__device__ inline unsigned short f2bf(float f) {
    unsigned int u = __float_as_uint(f);
    unsigned int r = (u + 0x7FFFu + ((u >> 16) & 1u)) >> 16;
    return (unsigned short)r;
}

// ws layout:
//  wsA    : B*192 f32          A_rel [B][16][12]
//  Mfinal : 1344 f32           M[21][16][4]
//  Gbf    : NVPAD*64 ushort    G[v][4k+d] = w[v][k]*{vx,vy,vz,1}[d]  (bf16)
//  Abf    : (3B+16)*64 ushort  Abf[3b+p][4k+d] = A_rel[b][k][4p+d]   (bf16)

__device__ inline void rodrigues9(float x, float y, float z, float R[9]) {
    float n2 = x * x + y * y + z * z + 1e-8f;
    float angle = sqrtf(n2);
    float inv = 1.0f / angle;
    float ax = x * inv, ay = y * inv, az = z * inv;
    float c = cosf(angle), s = sinf(angle);
    float C = 1.0f - c;
    R[0] = 1.0f - C * (ay * ay + az * az);
    R[1] = -s * az + C * ax * ay;
    R[2] = s * ay + C * ax * az;
    R[3] = s * az + C * ax * ay;
    R[4] = 1.0f - C * (ax * ax + az * az);
    R[5] = -s * ax + C * ay * az;
    R[6] = -s * ay + C * ax * az;
    R[7] = s * ax + C * ay * az;
    R[8] = 1.0f - C * (ax * ax + ay * ay);
}

// K1 (single prep+fk dispatch), 256 threads/block:
//  blocks [0, nFK):          FK per (batch, role), euler inline, jt inline.
//  blocks [nFK, nFK+21):     Mfinal direct (64 outputs each, 4 v-subgroups).
//  blocks [nFK+21, +272):    Gbf table.
__global__ __launch_bounds__(256) void prep_fk_kernel(
    const float* __restrict__ theta, const float* __restrict__ wrist,
    const float* __restrict__ hc, const float* __restrict__ hm,
    const float* __restrict__ vt, const float* __restrict__ jreg,
    const float* __restrict__ wts, float* __restrict__ wsA,
    float* __restrict__ Mfinal, unsigned short* __restrict__ Gbf,
    unsigned short* __restrict__ Abf, int total, int nFK) {
    int blk = blockIdx.x;
    int t = threadIdx.x;

    if (blk >= nFK + 21) {
        // Gbf table
        int idx = (blk - nFK - 21) * 256 + t;
        if (idx < NVPAD * 64) {
            int v = idx >> 6, i = idx & 63;
            int k = i >> 2, d = i & 3;
            float val = 0.f;
            if (v < NV) {
                float vh = (d == 3) ? 1.f : vt[v * 3 + d];
                val = wts[v * 16 + k] * vh;
            }
            Gbf[idx] = f2bf(val);
        }
        return;
    }
    if (blk >= nFK) {
        // Mfinal direct: q in [ (blk-nFK)*64, +64 ), 4 v-subgroups of 271
        __shared__ float sm[256];
        int q = (blk - nFK) * 64 + (t & 63);
        int vg = t >> 6;
        int j = q >> 6;                 // q/64, j<21
        int k = (q >> 2) & 15;
        int d = q & 3;
        int v0 = vg * 271, v1 = min(v0 + 271, NV);
        float acc = 0.f;
        for (int v = v0; v < v1; ++v) {
            float vh = (d == 3) ? 1.f : vt[v * 3 + d];
            acc += jreg[v * 21 + j] * wts[v * 16 + k] * vh;
        }
        sm[t] = acc;
        __syncthreads();
        if (vg == 0) Mfinal[q] = sm[t] + sm[t + 64] + sm[t + 128] + sm[t + 192];
        return;
    }

    // FK block: first compute jt (sj[48]) inline from vt/jreg.
    __shared__ float sred[240];
    __shared__ float sj[48];
    if (t < 240) {
        int g = t / 48, o = t - g * 48;
        int j = o / 3, c = o - j * 3;   // j < 16
        int v0 = g * 217, v1 = min(v0 + 217, NV);
        float acc = 0.f;
        for (int v = v0; v < v1; ++v) acc += vt[v * 3 + c] * jreg[v * 21 + j];
        sred[t] = acc;
    }
    __syncthreads();
    if (t < 48) sj[t] = sred[t] + sred[48 + t] + sred[96 + t] + sred[144 + t] + sred[192 + t];
    __syncthreads();

    int idx = blk * 256 + t;
    if (idx >= total) return;  // total = B*5
    int b = idx / 5, r = idx - b * 5;

    float e[9];
    {
        const float* th = theta + (size_t)b * 45;
        int base = 9 * r;
#pragma unroll
        for (int col = 0; col < 9; ++col) e[col] = hm[base + col];
        for (int k = 0; k < 45; ++k) {
            float tk = th[k];
            const float* hck = hc + k * 45 + base;
#pragma unroll
            for (int col = 0; col < 9; ++col) e[col] += tk * hck[col];
        }
    }

    float R[9];
    rodrigues9(wrist[b * 3 + 0], wrist[b * 3 + 1], wrist[b * 3 + 2], R);
    float J0x = sj[0], J0y = sj[1], J0z = sj[2];
    float Ap[12];
    Ap[0] = R[0]; Ap[1] = R[1]; Ap[2] = R[2]; Ap[3] = J0x;
    Ap[4] = R[3]; Ap[5] = R[4]; Ap[6] = R[5]; Ap[7] = J0y;
    Ap[8] = R[6]; Ap[9] = R[7]; Ap[10] = R[8]; Ap[11] = J0z;
    float* out = wsA + (size_t)b * 192;
    if (r == 0) {
#pragma unroll
        for (int row = 0; row < 3; ++row) {
            float a0 = Ap[row * 4 + 0], a1 = Ap[row * 4 + 1], a2 = Ap[row * 4 + 2];
            float a3 = Ap[row * 4 + 3] - (a0 * J0x + a1 * J0y + a2 * J0z);
            out[row * 4 + 0] = a0;
            out[row * 4 + 1] = a1;
            out[row * 4 + 2] = a2;
            out[row * 4 + 3] = a3;
            ushort4 h;
            h.x = f2bf(a0); h.y = f2bf(a1); h.z = f2bf(a2); h.w = f2bf(a3);
            *(ushort4*)(Abf + (size_t)(3 * b + row) * 64) = h;
        }
    }
    float px = J0x, py = J0y, pz = J0z;
#pragma unroll
    for (int s = 0; s < 3; ++s) {
        int i = r * 3 + s + 1;
        rodrigues9(e[3 * s + 0], e[3 * s + 1], e[3 * s + 2], R);
        float jx = sj[i * 3 + 0], jy = sj[i * 3 + 1], jz = sj[i * 3 + 2];
        float tx = jx - px, ty = jy - py, tz = jz - pz;
        float An[12];
#pragma unroll
        for (int row = 0; row < 3; ++row) {
            An[row * 4 + 0] = Ap[row * 4 + 0] * R[0] + Ap[row * 4 + 1] * R[3] + Ap[row * 4 + 2] * R[6];
            An[row * 4 + 1] = Ap[row * 4 + 0] * R[1] + Ap[row * 4 + 1] * R[4] + Ap[row * 4 + 2] * R[7];
            An[row * 4 + 2] = Ap[row * 4 + 0] * R[2] + Ap[row * 4 + 1] * R[5] + Ap[row * 4 + 2] * R[8];
            An[row * 4 + 3] = Ap[row * 4 + 3] + Ap[row * 4 + 0] * tx + Ap[row * 4 + 1] * ty + Ap[row * 4 + 2] * tz;
        }
        float* oi = out + i * 12;
#pragma unroll
        for (int row = 0; row < 3; ++row) {
            float a0 = An[row * 4 + 0], a1 = An[row * 4 + 1], a2 = An[row * 4 + 2];
            float a3 = An[row * 4 + 3] - (a0 * jx + a1 * jy + a2 * jz);
            oi[row * 4 + 0] = a0;
            oi[row * 4 + 1] = a1;
            oi[row * 4 + 2] = a2;
            oi[row * 4 + 3] = a3;
            ushort4 h;
            h.x = f2bf(a0); h.y = f2bf(a1); h.z = f2bf(a2); h.w = f2bf(a3);
            *(ushort4*)(Abf + (size_t)(3 * b + row) * 64 + 4 * i) = h;
        }
#pragma unroll
        for (int q = 0; q < 12; ++q) Ap[q] = An[q];
        px = jx; py = jy; pz = jz;
    }
}

// K2: blocks [0, nVB): MFMA GEMM, one block = 4 consecutive batches, all
//   NVPAD verts; LDS [12][1092] accumulate, then 52 KB contiguous NT stream.
// blocks [nVB, nVB + B/NBATCH): joints (f32 path) for NBATCH batches each.
#define SCW 1092
__global__ __launch_bounds__(256) void verts_joints_kernel(
    const float* __restrict__ wsA, const float* __restrict__ Mfinal,
    const unsigned short* __restrict__ Abf, const unsigned short* __restrict__ Gbf,
    float* __restrict__ verts, float* __restrict__ jout, int nVB) {
    int bid = blockIdx.x;
    int t = threadIdx.x;

    if (bid < nVB) {
        __shared__ float sC[12 * SCW];
        int b0 = bid * 4;               // 4 batches
        int w = t >> 6, lane = t & 63;
        int lrow = lane & 15, lk = lane >> 4;

        const unsigned short* Ar = Abf + (size_t)(b0 * 3 + lrow) * 64 + lk * 8;
        short8v a0 = *(const short8v*)Ar;
        short8v a1 = *(const short8v*)(Ar + 32);

        for (int vt4 = w; vt4 < NVPAD / 16; vt4 += 4) {
            int v = vt4 * 16 + lrow;
            const unsigned short* Br = Gbf + (size_t)v * 64 + lk * 8;
            short8v g0 = *(const short8v*)Br;
            short8v g1 = *(const short8v*)(Br + 32);
            f32x4 acc = {0.f, 0.f, 0.f, 0.f};
            acc = __builtin_amdgcn_mfma_f32_16x16x32_bf16(a0, g0, acc, 0, 0, 0);
            acc = __builtin_amdgcn_mfma_f32_16x16x32_bf16(a1, g1, acc, 0, 0, 0);
            if (lk < 3) {
                float* dst = &sC[(lk * 4) * SCW + vt4 * 16 + lrow];
#pragma unroll
                for (int q = 0; q < 4; ++q) dst[q * SCW] = acc[q];
            }
        }
        __syncthreads();

        float* outp = verts + (size_t)b0 * (NV * 3);
#pragma unroll 1
        for (int f = t; f < 3252; f += 256) {
            int bl = f / 813;
            int off = (f - bl * 813) * 4;
            f32x4 val;
#pragma unroll
            for (int j = 0; j < 4; ++j) {
                int o = off + j;
                int v_ = o / 3, p_ = o - v_ * 3;
                val[j] = sC[(bl * 3 + p_) * SCW + v_];
            }
            __builtin_nontemporal_store(val, (f32x4*)(outp + (size_t)f * 4));
        }
    } else {
        int b0 = (bid - nVB) * NBATCH;
        for (int o = t; o < NBATCH * 63; o += 256) {
            int bl = o / 63;
            int rem = o - bl * 63;
            int j = rem / 3;
            int c = rem - j * 3;
            const float* A = wsA + (size_t)(b0 + bl) * 192 + c * 4;
            const float* Mj = Mfinal + j * 64;
            float acc = 0.f;
#pragma unroll
            for (int k = 0; k < 16; ++k) {
                float4 av = *(const float4*)&A[k * 12];
                float4 m = *(const float4*)&Mj[k * 4];
                acc += av.x * m.x + av.y * m.y + av.z * m.z + av.w * m.w;
            }
            __builtin_nontemporal_store(acc, jout + (size_t)(b0 + bl) * 63 + rem);
        }
    }
}

extern "C" void kernel_launch(void* const* d_in, const int* in_sizes, int n_in,
                              void* d_out, int out_size, void* d_ws, size_t ws_size,
                              hipStream_t stream) {
    const float* theta = (const float*)d_in[1];
    const float* wrist = (const float*)d_in[2];
    const float* vtpl  = (const float*)d_in[3];
    const float* jreg  = (const float*)d_in[4];
    const float* hc    = (const float*)d_in[5];
    const float* hm    = (const float*)d_in[6];
    const float* wts   = (const float*)d_in[7];
    int B = in_sizes[1] / 45;  // 4096

    float* ws     = (float*)d_ws;
    float* wsA    = ws;                            // B*192 f32
    float* Mfinal = ws + (size_t)B * 192;          // 1344 f32
    unsigned short* Gbf = (unsigned short*)(Mfinal + 1344);  // NVPAD*64 ushort
    unsigned short* Abf = Gbf + (size_t)NVPAD * 64;          // (3B+16)*64 ushort
    float* verts  = (float*)d_out;
    float* jout   = verts + (size_t)B * NV * 3;

    int nFK = (B * 5 + 255) / 256;                 // 80
    int nG = (NVPAD * 64 + 255) / 256;             // 272
    prep_fk_kernel<<<nFK + 21 + nG, 256, 0, stream>>>(
        theta, wrist, hc, hm, vtpl, jreg, wts, wsA, Mfinal, Gbf, Abf, B * 5, nFK);
    int nVB = B / 4;                               // 1024 for B=4096
    verts_joints_kernel<<<nVB + B / NBATCH, 256, 0, stream>>>(
        wsA, Mfinal, Abf, Gbf, verts, jout, nVB);
}

// Round 18
// 52.887 us; speedup vs baseline: 1.4006x; 1.4006x over previous
//
#include <hip/hip_runtime.h>

#define NV 1084
#define NVPAD 1088
#define NBATCH 8   // batches per joints block

typedef __attribute__((ext_vector_type(8))) short short8v;
typedef __attribute__((ext_vector_type(4))) float f32x4;

__device__ inline unsigned short f2bf(float f) {
    unsigned int u = __float_as_uint(f);
    unsigned int r = (u + 0x7FFFu + ((u >> 16) & 1u)) >> 16;
    return (unsigned short)r;
}

// ws layout:
//  wsA    : B*192 f32          A_rel [B][16][12]
//  Mfinal : 1344 f32           M[21][16][4]
//  Gbf    : NVPAD*64 ushort    G[v][4k+d] = w[v][k]*{vx,vy,vz,1}[d]  (bf16)
//  Abf    : (3B+16)*64 ushort  Abf[3b+p][4k+d] = A_rel[b][k][4p+d]   (bf16)

__device__ inline void rodrigues9(float x, float y, float z, float R[9]) {
    float n2 = x * x + y * y + z * z + 1e-8f;
    float angle = sqrtf(n2);
    float inv = 1.0f / angle;
    float ax = x * inv, ay = y * inv, az = z * inv;
    float c = cosf(angle), s = sinf(angle);
    float C = 1.0f - c;
    R[0] = 1.0f - C * (ay * ay + az * az);
    R[1] = -s * az + C * ax * ay;
    R[2] = s * ay + C * ax * az;
    R[3] = s * az + C * ax * ay;
    R[4] = 1.0f - C * (ax * ax + az * az);
    R[5] = -s * ax + C * ay * az;
    R[6] = -s * ay + C * ax * az;
    R[7] = s * ax + C * ay * az;
    R[8] = 1.0f - C * (ax * ax + ay * ay);
}

// K1 (single prep+fk dispatch), 256 threads/block:
//  blocks [0, nFK):           FK per (batch, role); euler inline; jt inline
//                             with 8-way unrolled load chains.
//  blocks [nFK, nFK+84):      Mfinal: 16 q-outputs each, 16 threads/q over
//                             68-vert ranges, 4-way unrolled, LDS tree.
//  blocks [nFK+84, +272):     Gbf table (one element per thread).
__global__ __launch_bounds__(256) void prep_fk_kernel(
    const float* __restrict__ theta, const float* __restrict__ wrist,
    const float* __restrict__ hc, const float* __restrict__ hm,
    const float* __restrict__ vt, const float* __restrict__ jreg,
    const float* __restrict__ wts, float* __restrict__ wsA,
    float* __restrict__ Mfinal, unsigned short* __restrict__ Gbf,
    unsigned short* __restrict__ Abf, int total, int nFK) {
    int blk = blockIdx.x;
    int t = threadIdx.x;

    if (blk >= nFK + 84) {
        // Gbf table
        int idx = (blk - nFK - 84) * 256 + t;
        if (idx < NVPAD * 64) {
            int v = idx >> 6, i = idx & 63;
            int k = i >> 2, d = i & 3;
            float val = 0.f;
            if (v < NV) {
                float vh = (d == 3) ? 1.f : vt[v * 3 + d];
                val = wts[v * 16 + k] * vh;
            }
            Gbf[idx] = f2bf(val);
        }
        return;
    }
    if (blk >= nFK) {
        // Mfinal: block handles q in [m*16, m*16+16); t = vg*16 + ql.
        __shared__ float sm[256];
        int m = blk - nFK;
        int ql = t & 15, vg = t >> 4;
        int q = m * 16 + ql;
        int j = q >> 6;                 // q/64, j<21
        int k = (q >> 2) & 15;
        int d = q & 3;
        int v0 = vg * 68, v1 = min(v0 + 68, NV);
        float a0 = 0.f, a1 = 0.f, a2 = 0.f, a3 = 0.f;
        int v = v0;
        for (; v + 4 <= v1; v += 4) {
            float h0 = (d == 3) ? 1.f : vt[(v + 0) * 3 + d];
            float h1 = (d == 3) ? 1.f : vt[(v + 1) * 3 + d];
            float h2 = (d == 3) ? 1.f : vt[(v + 2) * 3 + d];
            float h3 = (d == 3) ? 1.f : vt[(v + 3) * 3 + d];
            a0 += jreg[(v + 0) * 21 + j] * wts[(v + 0) * 16 + k] * h0;
            a1 += jreg[(v + 1) * 21 + j] * wts[(v + 1) * 16 + k] * h1;
            a2 += jreg[(v + 2) * 21 + j] * wts[(v + 2) * 16 + k] * h2;
            a3 += jreg[(v + 3) * 21 + j] * wts[(v + 3) * 16 + k] * h3;
        }
        float acc = (a0 + a1) + (a2 + a3);
        for (; v < v1; ++v) {
            float h = (d == 3) ? 1.f : vt[v * 3 + d];
            acc += jreg[v * 21 + j] * wts[v * 16 + k] * h;
        }
        sm[t] = acc;
        __syncthreads();
        if (vg == 0) {
            float s = 0.f;
#pragma unroll
            for (int u = 0; u < 16; ++u) s += sm[ql + 16 * u];
            Mfinal[q] = s;
        }
        return;
    }

    // FK block: jt (sj[48]) inline, 8-way unrolled.
    __shared__ float sred[240];
    __shared__ float sj[48];
    if (t < 240) {
        int g = t / 48, o = t - g * 48;
        int j = o / 3, c = o - j * 3;   // j < 16
        int v0 = g * 217, v1 = min(v0 + 217, NV);
        float a0 = 0.f, a1 = 0.f, a2 = 0.f, a3 = 0.f;
        float a4 = 0.f, a5 = 0.f, a6 = 0.f, a7 = 0.f;
        int v = v0;
        for (; v + 8 <= v1; v += 8) {
            a0 += vt[(v + 0) * 3 + c] * jreg[(v + 0) * 21 + j];
            a1 += vt[(v + 1) * 3 + c] * jreg[(v + 1) * 21 + j];
            a2 += vt[(v + 2) * 3 + c] * jreg[(v + 2) * 21 + j];
            a3 += vt[(v + 3) * 3 + c] * jreg[(v + 3) * 21 + j];
            a4 += vt[(v + 4) * 3 + c] * jreg[(v + 4) * 21 + j];
            a5 += vt[(v + 5) * 3 + c] * jreg[(v + 5) * 21 + j];
            a6 += vt[(v + 6) * 3 + c] * jreg[(v + 6) * 21 + j];
            a7 += vt[(v + 7) * 3 + c] * jreg[(v + 7) * 21 + j];
        }
        float acc = ((a0 + a1) + (a2 + a3)) + ((a4 + a5) + (a6 + a7));
        for (; v < v1; ++v) acc += vt[v * 3 + c] * jreg[v * 21 + j];
        sred[t] = acc;
    }
    __syncthreads();
    if (t < 48)
        sj[t] = sred[t] + sred[48 + t] + sred[96 + t] + sred[144 + t] + sred[192 + t];
    __syncthreads();

    int idx = blk * 256 + t;
    if (idx >= total) return;  // total = B*5
    int b = idx / 5, r = idx - b * 5;

    float e[9];
    {
        const float* th = theta + (size_t)b * 45;
        int base = 9 * r;
#pragma unroll
        for (int col = 0; col < 9; ++col) e[col] = hm[base + col];
        for (int k = 0; k < 45; ++k) {
            float tk = th[k];
            const float* hck = hc + k * 45 + base;
#pragma unroll
            for (int col = 0; col < 9; ++col) e[col] += tk * hck[col];
        }
    }

    float R[9];
    rodrigues9(wrist[b * 3 + 0], wrist[b * 3 + 1], wrist[b * 3 + 2], R);
    float J0x = sj[0], J0y = sj[1], J0z = sj[2];
    float Ap[12];
    Ap[0] = R[0]; Ap[1] = R[1]; Ap[2] = R[2]; Ap[3] = J0x;
    Ap[4] = R[3]; Ap[5] = R[4]; Ap[6] = R[5]; Ap[7] = J0y;
    Ap[8] = R[6]; Ap[9] = R[7]; Ap[10] = R[8]; Ap[11] = J0z;
    float* out = wsA + (size_t)b * 192;
    if (r == 0) {
#pragma unroll
        for (int row = 0; row < 3; ++row) {
            float a0 = Ap[row * 4 + 0], a1 = Ap[row * 4 + 1], a2 = Ap[row * 4 + 2];
            float a3 = Ap[row * 4 + 3] - (a0 * J0x + a1 * J0y + a2 * J0z);
            out[row * 4 + 0] = a0;
            out[row * 4 + 1] = a1;
            out[row * 4 + 2] = a2;
            out[row * 4 + 3] = a3;
            ushort4 h;
            h.x = f2bf(a0); h.y = f2bf(a1); h.z = f2bf(a2); h.w = f2bf(a3);
            *(ushort4*)(Abf + (size_t)(3 * b + row) * 64) = h;
        }
    }
    float px = J0x, py = J0y, pz = J0z;
#pragma unroll
    for (int s = 0; s < 3; ++s) {
        int i = r * 3 + s + 1;
        rodrigues9(e[3 * s + 0], e[3 * s + 1], e[3 * s + 2], R);
        float jx = sj[i * 3 + 0], jy = sj[i * 3 + 1], jz = sj[i * 3 + 2];
        float tx = jx - px, ty = jy - py, tz = jz - pz;
        float An[12];
#pragma unroll
        for (int row = 0; row < 3; ++row) {
            An[row * 4 + 0] = Ap[row * 4 + 0] * R[0] + Ap[row * 4 + 1] * R[3] + Ap[row * 4 + 2] * R[6];
            An[row * 4 + 1] = Ap[row * 4 + 0] * R[1] + Ap[row * 4 + 1] * R[4] + Ap[row * 4 + 2] * R[7];
            An[row * 4 + 2] = Ap[row * 4 + 0] * R[2] + Ap[row * 4 + 1] * R[5] + Ap[row * 4 + 2] * R[8];
            An[row * 4 + 3] = Ap[row * 4 + 3] + Ap[row * 4 + 0] * tx + Ap[row * 4 + 1] * ty + Ap[row * 4 + 2] * tz;
        }
        float* oi = out + i * 12;
#pragma unroll
        for (int row = 0; row < 3; ++row) {
            float a0 = An[row * 4 + 0], a1 = An[row * 4 + 1], a2 = An[row * 4 + 2];
            float a3 = An[row * 4 + 3] - (a0 * jx + a1 * jy + a2 * jz);
            oi[row * 4 + 0] = a0;
            oi[row * 4 + 1] = a1;
            oi[row * 4 + 2] = a2;
            oi[row * 4 + 3] = a3;
            ushort4 h;
            h.x = f2bf(a0); h.y = f2bf(a1); h.z = f2bf(a2); h.w = f2bf(a3);
            *(ushort4*)(Abf + (size_t)(3 * b + row) * 64 + 4 * i) = h;
        }
#pragma unroll
        for (int q = 0; q < 12; ++q) Ap[q] = An[q];
        px = jx; py = jy; pz = jz;
    }
}

// K2: blocks [0, nVB): MFMA GEMM, one block = 4 consecutive batches, all
//   NVPAD verts; LDS [12][1092] accumulate, then 52 KB contiguous NT stream.
// blocks [nVB, nVB + B/NBATCH): joints (f32 path) for NBATCH batches each.
#define SCW 1092
__global__ __launch_bounds__(256) void verts_joints_kernel(
    const float* __restrict__ wsA, const float* __restrict__ Mfinal,
    const unsigned short* __restrict__ Abf, const unsigned short* __restrict__ Gbf,
    float* __restrict__ verts, float* __restrict__ jout, int nVB) {
    int bid = blockIdx.x;
    int t = threadIdx.x;

    if (bid < nVB) {
        __shared__ float sC[12 * SCW];
        int b0 = bid * 4;               // 4 batches
        int w = t >> 6, lane = t & 63;
        int lrow = lane & 15, lk = lane >> 4;

        const unsigned short* Ar = Abf + (size_t)(b0 * 3 + lrow) * 64 + lk * 8;
        short8v a0 = *(const short8v*)Ar;
        short8v a1 = *(const short8v*)(Ar + 32);

        for (int vt4 = w; vt4 < NVPAD / 16; vt4 += 4) {
            int v = vt4 * 16 + lrow;
            const unsigned short* Br = Gbf + (size_t)v * 64 + lk * 8;
            short8v g0 = *(const short8v*)Br;
            short8v g1 = *(const short8v*)(Br + 32);
            f32x4 acc = {0.f, 0.f, 0.f, 0.f};
            acc = __builtin_amdgcn_mfma_f32_16x16x32_bf16(a0, g0, acc, 0, 0, 0);
            acc = __builtin_amdgcn_mfma_f32_16x16x32_bf16(a1, g1, acc, 0, 0, 0);
            if (lk < 3) {
                float* dst = &sC[(lk * 4) * SCW + vt4 * 16 + lrow];
#pragma unroll
                for (int q = 0; q < 4; ++q) dst[q * SCW] = acc[q];
            }
        }
        __syncthreads();

        float* outp = verts + (size_t)b0 * (NV * 3);
#pragma unroll 1
        for (int f = t; f < 3252; f += 256) {
            int bl = f / 813;
            int off = (f - bl * 813) * 4;
            f32x4 val;
#pragma unroll
            for (int j = 0; j < 4; ++j) {
                int o = off + j;
                int v_ = o / 3, p_ = o - v_ * 3;
                val[j] = sC[(bl * 3 + p_) * SCW + v_];
            }
            __builtin_nontemporal_store(val, (f32x4*)(outp + (size_t)f * 4));
        }
    } else {
        int b0 = (bid - nVB) * NBATCH;
        for (int o = t; o < NBATCH * 63; o += 256) {
            int bl = o / 63;
            int rem = o - bl * 63;
            int j = rem / 3;
            int c = rem - j * 3;
            const float* A = wsA + (size_t)(b0 + bl) * 192 + c * 4;
            const float* Mj = Mfinal + j * 64;
            float acc = 0.f;
#pragma unroll
            for (int k = 0; k < 16; ++k) {
                float4 av = *(const float4*)&A[k * 12];
                float4 m = *(const float4*)&Mj[k * 4];
                acc += av.x * m.x + av.y * m.y + av.z * m.z + av.w * m.w;
            }
            __builtin_nontemporal_store(acc, jout + (size_t)(b0 + bl) * 63 + rem);
        }
    }
}

extern "C" void kernel_launch(void* const* d_in, const int* in_sizes, int n_in,
                              void* d_out, int out_size, void* d_ws, size_t ws_size,
                              hipStream_t stream) {
    const float* theta = (const float*)d_in[1];
    const float* wrist = (const float*)d_in[2];
    const float* vtpl  = (const float*)d_in[3];
    const float* jreg  = (const float*)d_in[4];
    const float* hc    = (const float*)d_in[5];
    const float* hm    = (const float*)d_in[6];
    const float* wts   = (const float*)d_in[7];
    int B = in_sizes[1] / 45;  // 4096

    float* ws     = (float*)d_ws;
    float* wsA    = ws;                            // B*192 f32
    float* Mfinal = ws + (size_t)B * 192;          // 1344 f32
    unsigned short* Gbf = (unsigned short*)(Mfinal + 1344);  // NVPAD*64 ushort
    unsigned short* Abf = Gbf + (size_t)NVPAD * 64;          // (3B+16)*64 ushort
    float* verts  = (float*)d_out;
    float* jout   = verts + (size_t)B * NV * 3;

    int nFK = (B * 5 + 255) / 256;                 // 80
    int nG = (NVPAD * 64 + 255) / 256;             // 272
    prep_fk_kernel<<<nFK + 84 + nG, 256, 0, stream>>>(
        theta, wrist, hc, hm, vtpl, jreg, wts, wsA, Mfinal, Gbf, Abf, B * 5, nFK);
    int nVB = B / 4;                               // 1024 for B=4096
    verts_joints_kernel<<<nVB + B / NBATCH, 256, 0, stream>>>(
        wsA, Mfinal, Abf, Gbf, verts, jout, nVB);
}